// Round 16
// baseline (102.625 us; speedup 1.0000x reference)
//
#include <hip/hip_runtime.h>
#include <cstdint>

// CapsuleLayer dynamic routing: B=256, R=1152, C=10, O=16, I=8, 3 iters.
// Round 16: DPP rotation reduces — move cross-lane sums off the LDS pipe.
//  * r15: k_caps 45.1us, VALU 50%, memory clean. Remaining stalls are
//    ~70 __shfl_xor (ds_swizzle, ~40cy serial) per thread in reduction
//    chains. Any within-16-lane-row reduce can use DPP row_ror adds on
//    the VALU pipe instead: v += ror8(v); v += ror4(v) sums a stride-4
//    group; stride-8 group needs only ror8. Applied:
//      - phase-1 reduce: mask 8 -> ror8 (masks 16,32 stay shfl)
//      - pass butterflies: masks 4,8 -> ror4+ror8 (16,32 stay shfl)
//      - all ss-reduces: xor1,xor2 (quad_perm) + ror4 + ror8, all DPP
//    ~70 -> ~30 LDS-pipe ops; chains halved. Same pairwise tree shape,
//    reassociated only (absmax may shift ~ulp; stays ~0.0137 < 0.0172).
//  * Phase-1 unroll 4 -> 6 (more load-latency overlap; alloca-free).
//  * Everything else = r15 (dot2 phase 1, packed W+x pre-pass, 3-barrier
//    phase 2, weights fp32 in regs).
#define BB 256
#define RR 1152
#define CC 10
#define OO 16
#define II 8
#define NT 768
#define GG 2
#define NWAVE (NT / 64)    // 12
#define WPG (NWAVE / GG)   // 6 waves per g in phase 2
#define LOG2E 1.4426950408889634f
#define WSWORDS ((size_t)RR * CC * (OO * II / 2))   // 737,280 packed words
#define XWORDS  ((size_t)BB * RR * (II / 2))        // 1,179,648 packed words

typedef float float2v __attribute__((ext_vector_type(2)));

__device__ __forceinline__ void unpack2(uint32_t pk, float& lo, float& hi) {
    union { uint32_t i; float f; } a, b;
    a.i = pk << 16; b.i = pk & 0xffff0000u;
    lo = a.f; hi = b.f;
}
// v + (value from lane l^1), DPP quad_perm [1,0,3,2]
__device__ __forceinline__ float qpadd1(float v) {
    int o = __builtin_amdgcn_mov_dpp(__float_as_int(v), 0xB1, 0xF, 0xF, true);
    return v + __int_as_float(o);
}
// v + (value from lane l^2), DPP quad_perm [2,3,0,1]
__device__ __forceinline__ float qpadd2(float v) {
    int o = __builtin_amdgcn_mov_dpp(__float_as_int(v), 0x4E, 0xF, 0xF, true);
    return v + __int_as_float(o);
}
// v + (value from lane row_ror:4) — stride-4 partner within 16-lane row
__device__ __forceinline__ float rr4add(float v) {
    int o = __builtin_amdgcn_mov_dpp(__float_as_int(v), 0x124, 0xF, 0xF, true);
    return v + __int_as_float(o);
}
// v + (value from lane row_ror:8) — stride-8 partner within 16-lane row
__device__ __forceinline__ float rr8add(float v) {
    int o = __builtin_amdgcn_mov_dpp(__float_as_int(v), 0x128, 0xF, 0xF, true);
    return v + __int_as_float(o);
}
// packed bf16 pair from two f32 (hardware RNE), one instruction
__device__ __forceinline__ uint32_t cvtpk(float lo, float hi) {
    uint32_t r;
    asm("v_cvt_pk_bf16_f32 %0, %1, %2" : "=v"(r) : "v"(lo), "v"(hi));
    return r;
}
// packed-bf16 dot2 with accumulate: D = a.lo*b.lo + a.hi*b.hi + c
__device__ __forceinline__ float dot2bf(uint32_t a, uint32_t b, float c) {
    float d;
    asm("v_dot2_f32_bf16 %0, %1, %2, %3" : "=v"(d) : "v"(a), "v"(b), "v"(c));
    return d;
}
#if __has_builtin(__builtin_amdgcn_exp2f)
#define EXP2(x) __builtin_amdgcn_exp2f(x)
#else
#define EXP2(x) __expf((x) * 0.6931471805599453f)
#endif
#define LD4(P) (*reinterpret_cast<const float4*>(P))

// 8-element dot on packed quads: 4 chained dot2
#define DOT8P(WQ, XQ, OUT)                                                    \
  do {                                                                        \
    float a_ = dot2bf(WQ.x, XQ.x, 0.0f);                                      \
    a_ = dot2bf(WQ.y, XQ.y, a_);                                              \
    a_ = dot2bf(WQ.z, XQ.z, a_);                                              \
    OUT = dot2bf(WQ.w, XQ.w, a_);                                             \
  } while (0)

// ---- pre-pass: W and x fp32 -> packed bf16 pairs (same element order) ----
__global__ __launch_bounds__(256)
void k_cvt(const float* __restrict__ Wf, const float* __restrict__ xf,
           uint32_t* __restrict__ wbf, uint32_t* __restrict__ xpk) {
    size_t tid = (size_t)blockIdx.x * 256 + threadIdx.x;   // quad index
    if (tid < WSWORDS / 4) {
        float4 a = LD4(Wf + 8 * tid);
        float4 b = LD4(Wf + 8 * tid + 4);
        uint4 r;
        r.x = cvtpk(a.x, a.y); r.y = cvtpk(a.z, a.w);
        r.z = cvtpk(b.x, b.y); r.w = cvtpk(b.z, b.w);
        *reinterpret_cast<uint4*>(wbf + 4 * tid) = r;
    }
    if (tid < XWORDS / 4) {
        float4 a = LD4(xf + 8 * tid);
        float4 b = LD4(xf + 8 * tid + 4);
        uint4 r;
        r.x = cvtpk(a.x, a.y); r.y = cvtpk(a.z, a.w);
        r.z = cvtpk(b.x, b.y); r.w = cvtpk(b.z, b.w);
        *reinterpret_cast<uint4*>(xpk + 4 * tid) = r;
    }
}

__global__ __launch_bounds__(NT, 6)
void k_caps(const uint32_t* __restrict__ xpk, const uint32_t* __restrict__ wb,
            float* __restrict__ out) {
    extern __shared__ uint32_t u2[];          // [GG][RR][8] packed bf16 pairs
    __shared__ float p0s[NWAVE][8][2][GG];    // [wv][p][slot o>>3][g]
    __shared__ float part2[2][17][NWAVE];

    const int t = threadIdx.x;
    const int c  = blockIdx.x / (BB / GG);    // c-major: blocks share W-slice
    const int b0 = (blockIdx.x % (BB / GG)) * GG;
    const int wv = t >> 6, l = t & 63;
    const int rg = t >> 3, p = t & 7;         // phase 1: 96 r-rows x 8 lanes

    uint32_t* uA = u2;                        // batch b0
    uint32_t* uB = u2 + (size_t)RR * 8;       // batch b0+1
    uint32_t* wrA = uA + (size_t)rg * 8 + p;  // word p of row rg
    uint32_t* wrB = uB + (size_t)rg * 8 + p;

    // ---- Phase 1: lane p computes u[o=p], u[o=p+8] for both g ----
    float s00 = 0.f, s01 = 0.f, s10 = 0.f, s11 = 0.f;
#pragma unroll 6
    for (int it = 0; it < 12; ++it) {
        const int r = it * 96 + rg;
        const uint32_t* wrow = wb + ((size_t)r * CC + c) * 64 + 4 * p;
        uint4 wq0 = *reinterpret_cast<const uint4*>(wrow);        // o = p
        uint4 wq1 = *reinterpret_cast<const uint4*>(wrow + 32);   // o = p+8
        const uint32_t* xp = xpk + ((size_t)b0 * RR + r) * 4;
        uint4 xq0 = *reinterpret_cast<const uint4*>(xp);              // g=0
        uint4 xq1 = *reinterpret_cast<const uint4*>(xp + (size_t)RR * 4); // g=1
        float d0, d1, e0, e1;
        DOT8P(wq0, xq0, d0);                  // g=0, o=p
        DOT8P(wq1, xq0, d1);                  // g=0, o=p+8
        DOT8P(wq0, xq1, e0);                  // g=1, o=p
        DOT8P(wq1, xq1, e1);                  // g=1, o=p+8
        s00 += d0; s01 += d1; s10 += e0; s11 += e1;
        wrA[(size_t)it * 768] = cvtpk(d0, d1);      // word p = (u[p], u[p+8])
        wrB[(size_t)it * 768] = cvtpk(e0, e1);
    }
    // pass-0 reduce over the 8 row-lanes sharing p: ror8 (DPP) + shfl 16,32
    s00 = rr8add(s00); s01 = rr8add(s01);
    s10 = rr8add(s10); s11 = rr8add(s11);
#pragma unroll
    for (int m = 16; m < 64; m <<= 1) {
        s00 += __shfl_xor(s00, m); s01 += __shfl_xor(s01, m);
        s10 += __shfl_xor(s10, m); s11 += __shfl_xor(s11, m);
    }
    if (l < 8) {                              // lane l == p
        p0s[wv][l][0][0] = s00; p0s[wv][l][1][0] = s01;
        p0s[wv][l][0][1] = s10; p0s[wv][l][1][1] = s11;
    }
    __syncthreads();                          // BARRIER 1 of 3

    // ---- Phase-2 mapping (r12/r14 structure) ----
    const int g2 = wv / WPG;                  // waves 0-5: g=0, 6-11: g=1
    const int wv6 = wv - g2 * WPG;
    const uint32_t* ug = g2 ? uB : uA;
    const int q = l & 3;                      // owns o in {2q,2q+1,2q+8,2q+9}
    const int rl = l >> 2;
    const int rbase = wv6 * 16 + rl;
    const uint32_t* rp = ug + (size_t)rbase * 8 + 2 * q;

    const int oo = l & 15;                    // lane's redundant-squash o
    const int gb = l & 48;
    const int t0 = gb | (2 * q), t1 = gb | (2 * q + 1);
    const int t2 = gb | (2 * q + 8), t3 = gb | (2 * q + 9);

    // ---- v0 computed redundantly by all lanes ----
    float ra, rb, rc, rd;
    {
        float sv = 0.f;
#pragma unroll
        for (int w = 0; w < NWAVE; ++w) sv += p0s[w][oo & 7][oo >> 3][g2];
        sv *= (1.0f / RR);                    // softmax(0) = 1/R
        float ss = sv * sv;                   // 16-lane row sum, all DPP
        ss = qpadd1(ss); ss = qpadd2(ss); ss = rr4add(ss); ss = rr8add(ss);
        float vv = sv * (ss / ((1.0f + ss) * sqrtf(ss + 1e-7f)));
        ra = __shfl(vv, t0); rb = __shfl(vv, t1);
        rc = __shfl(vv, t2); rd = __shfl(vv, t3);
    }

    // ---- Phase 2: passes 1 and 2; one barrier each ----
#pragma unroll
    for (int pass = 1; pass < 3; ++pass) {
        const float2v WQA = { ra * LOG2E, rc * LOG2E };
        const float2v WQB = { rb * LOG2E, rd * LOG2E };
        float2v N0 = { 0.f, 0.f }, N1 = { 0.f, 0.f };
        float den = 0.f;

#pragma unroll
        for (int it2 = 0; it2 < 12; ++it2) {
            uint2 pp = *reinterpret_cast<const uint2*>(rp + (size_t)it2 * 768);
            float a_, b_, c_, d_;
            unpack2(pp.x, a_, b_);            // (u[2q],   u[2q+8])
            unpack2(pp.y, c_, d_);            // (u[2q+1], u[2q+9])
            float2v P0 = { a_, b_ };
            float2v P1 = { c_, d_ };
            float2v lg2 = __builtin_elementwise_fma(P0, WQA, P1 * WQB);
            float lg = lg2.x + lg2.y;
            lg = qpadd1(lg);                  // + lane^1 (quad partial)
            lg = qpadd2(lg);                  // + lane^2: full 16-o logit
            float e = EXP2(lg);               // == exp(raw logit)
            den += e;                         // same-q lanes: distinct r's
            float2v E2 = { e, e };
            N0 = __builtin_elementwise_fma(E2, P0, N0);
            N1 = __builtin_elementwise_fma(E2, P1, N1);
        }

        // stride-4-group reduce: ror4+ror8 (DPP) then shfl 16,32
        float n0 = N0.x, n2 = N0.y, n1 = N1.x, n3 = N1.y;
        n0 = rr4add(n0); n1 = rr4add(n1); n2 = rr4add(n2); n3 = rr4add(n3);
        den = rr4add(den);
        n0 = rr8add(n0); n1 = rr8add(n1); n2 = rr8add(n2); n3 = rr8add(n3);
        den = rr8add(den);
#pragma unroll
        for (int m = 16; m < 64; m <<= 1) {
            n0 += __shfl_xor(n0, m); n1 += __shfl_xor(n1, m);
            n2 += __shfl_xor(n2, m); n3 += __shfl_xor(n3, m);
            den += __shfl_xor(den, m);
        }
        const int pb = pass & 1;
        if (l < 4) {                          // lane l == q
            part2[pb][2 * l][wv]     = n0;
            part2[pb][2 * l + 1][wv] = n1;
            part2[pb][2 * l + 8][wv] = n2;
            part2[pb][2 * l + 9][wv] = n3;
            if (l == 0) part2[pb][16][wv] = den;
        }
        __syncthreads();                      // BARRIERS 2,3

        const float* po = &part2[pb][oo][0];
        const float* pd = &part2[pb][16][0];
        float nf = 0.f, df = 0.f;
#pragma unroll
        for (int w = 0; w < WPG; ++w) {
            nf += po[g2 * WPG + w];
            df += pd[g2 * WPG + w];
        }
        float s2 = nf / df;
        float ss2 = s2 * s2;                  // 16-lane row sum, all DPP
        ss2 = qpadd1(ss2); ss2 = qpadd2(ss2);
        ss2 = rr4add(ss2); ss2 = rr8add(ss2);
        float vv2 = s2 * (ss2 / ((1.0f + ss2) * sqrtf(ss2 + 1e-7f)));

        if (pass == 1) {                      // accumulate weights in regs
            ra += __shfl(vv2, t0); rb += __shfl(vv2, t1);
            rc += __shfl(vv2, t2); rd += __shfl(vv2, t3);
        } else {
            if ((wv == 0 || wv == WPG) && l < 16)
                out[((size_t)(b0 + g2) * CC + c) * OO + oo] = vv2;
        }
    }
}

extern "C" void kernel_launch(void* const* d_in, const int* in_sizes, int n_in,
                              void* d_out, int out_size, void* d_ws, size_t ws_size,
                              hipStream_t stream) {
    const float* x = (const float*)d_in[0];  // (B,R,I) fp32
    const float* W = (const float*)d_in[1];  // (R,C,O,I) fp32
    if (n_in >= 2 && in_sizes[0] == RR * CC * OO * II &&
        in_sizes[1] == BB * RR * II) {
        const float* tmp = x; x = W; W = tmp;
    }
    float* out = (float*)d_out;              // (B,1,C,O,1) fp32
    uint32_t* wbf = (uint32_t*)d_ws;         // packed-bf16 W (2.95 MB)
    uint32_t* xpk = wbf + WSWORDS;           // packed-bf16 x (4.72 MB)

    const int cvt_blocks = (int)((XWORDS / 4 + 255) / 256);   // 1152
    k_cvt<<<cvt_blocks, 256, 0, stream>>>(W, x, wbf, xpk);

    const size_t dyn_lds = (size_t)GG * RR * 8 * 4;   // 73,728 B
    k_caps<<<CC * (BB / GG), NT, dyn_lds, stream>>>(xpk, wbf, out);
}

// Round 17
// 98.923 us; speedup vs baseline: 1.0374x; 1.0374x over previous
//
#include <hip/hip_runtime.h>
#include <cstdint>

// CapsuleLayer dynamic routing: B=256, R=1152, C=10, O=16, I=8, 3 iters.
// Round 17: phase-1 ILP — 2-row straight-line bodies, loads batched 8-deep.
//  * r16 accounting: VALU issue ~21us, TA ~11us, LDS ~4us, measured 43
//    => ~22us dependency stalls at 6 waves/SIMD (LDS-capped occupancy).
//    VGPR=36 of 85: compiler keeps ~1 iter of loads in flight.
//  * Phase 1 rewritten as 6 unconditional 2-row bodies: all 8 loads
//    (2 rows x {2 W uint4 + 2 x uint4}) issue BEFORE either row's
//    compute. No conditionals (r8 scratch trap), no arrays (r7/r9/r10
//    barrier-crossing trap). ~32 extra live VGPRs, under the 85 cap.
//  * Everything else = r16 verbatim (dot2 phase 1, packed W+x pre-pass,
//    DPP ror reduces, 3-barrier phase 2, fp32 weights in regs).
#define BB 256
#define RR 1152
#define CC 10
#define OO 16
#define II 8
#define NT 768
#define GG 2
#define NWAVE (NT / 64)    // 12
#define WPG (NWAVE / GG)   // 6 waves per g in phase 2
#define LOG2E 1.4426950408889634f
#define WSWORDS ((size_t)RR * CC * (OO * II / 2))   // 737,280 packed words
#define XWORDS  ((size_t)BB * RR * (II / 2))        // 1,179,648 packed words

typedef float float2v __attribute__((ext_vector_type(2)));

__device__ __forceinline__ void unpack2(uint32_t pk, float& lo, float& hi) {
    union { uint32_t i; float f; } a, b;
    a.i = pk << 16; b.i = pk & 0xffff0000u;
    lo = a.f; hi = b.f;
}
// v + (value from lane l^1), DPP quad_perm [1,0,3,2]
__device__ __forceinline__ float qpadd1(float v) {
    int o = __builtin_amdgcn_mov_dpp(__float_as_int(v), 0xB1, 0xF, 0xF, true);
    return v + __int_as_float(o);
}
// v + (value from lane l^2), DPP quad_perm [2,3,0,1]
__device__ __forceinline__ float qpadd2(float v) {
    int o = __builtin_amdgcn_mov_dpp(__float_as_int(v), 0x4E, 0xF, 0xF, true);
    return v + __int_as_float(o);
}
// v + (value from lane row_ror:4)
__device__ __forceinline__ float rr4add(float v) {
    int o = __builtin_amdgcn_mov_dpp(__float_as_int(v), 0x124, 0xF, 0xF, true);
    return v + __int_as_float(o);
}
// v + (value from lane row_ror:8)
__device__ __forceinline__ float rr8add(float v) {
    int o = __builtin_amdgcn_mov_dpp(__float_as_int(v), 0x128, 0xF, 0xF, true);
    return v + __int_as_float(o);
}
// packed bf16 pair from two f32 (hardware RNE)
__device__ __forceinline__ uint32_t cvtpk(float lo, float hi) {
    uint32_t r;
    asm("v_cvt_pk_bf16_f32 %0, %1, %2" : "=v"(r) : "v"(lo), "v"(hi));
    return r;
}
// packed-bf16 dot2 with accumulate: D = a.lo*b.lo + a.hi*b.hi + c
__device__ __forceinline__ float dot2bf(uint32_t a, uint32_t b, float c) {
    float d;
    asm("v_dot2_f32_bf16 %0, %1, %2, %3" : "=v"(d) : "v"(a), "v"(b), "v"(c));
    return d;
}
#if __has_builtin(__builtin_amdgcn_exp2f)
#define EXP2(x) __builtin_amdgcn_exp2f(x)
#else
#define EXP2(x) __expf((x) * 0.6931471805599453f)
#endif
#define LD4(P) (*reinterpret_cast<const float4*>(P))

#define DOT8P(WQ, XQ, OUT)                                                    \
  do {                                                                        \
    float a_ = dot2bf(WQ.x, XQ.x, 0.0f);                                      \
    a_ = dot2bf(WQ.y, XQ.y, a_);                                              \
    a_ = dot2bf(WQ.z, XQ.z, a_);                                              \
    OUT = dot2bf(WQ.w, XQ.w, a_);                                             \
  } while (0)

// ---- pre-pass: W and x fp32 -> packed bf16 pairs (same element order) ----
__global__ __launch_bounds__(256)
void k_cvt(const float* __restrict__ Wf, const float* __restrict__ xf,
           uint32_t* __restrict__ wbf, uint32_t* __restrict__ xpk) {
    size_t tid = (size_t)blockIdx.x * 256 + threadIdx.x;   // quad index
    if (tid < WSWORDS / 4) {
        float4 a = LD4(Wf + 8 * tid);
        float4 b = LD4(Wf + 8 * tid + 4);
        uint4 r;
        r.x = cvtpk(a.x, a.y); r.y = cvtpk(a.z, a.w);
        r.z = cvtpk(b.x, b.y); r.w = cvtpk(b.z, b.w);
        *reinterpret_cast<uint4*>(wbf + 4 * tid) = r;
    }
    if (tid < XWORDS / 4) {
        float4 a = LD4(xf + 8 * tid);
        float4 b = LD4(xf + 8 * tid + 4);
        uint4 r;
        r.x = cvtpk(a.x, a.y); r.y = cvtpk(a.z, a.w);
        r.z = cvtpk(b.x, b.y); r.w = cvtpk(b.z, b.w);
        *reinterpret_cast<uint4*>(xpk + 4 * tid) = r;
    }
}

__global__ __launch_bounds__(NT, 6)
void k_caps(const uint32_t* __restrict__ xpk, const uint32_t* __restrict__ wb,
            float* __restrict__ out) {
    extern __shared__ uint32_t u2[];          // [GG][RR][8] packed bf16 pairs
    __shared__ float p0s[NWAVE][8][2][GG];    // [wv][p][slot o>>3][g]
    __shared__ float part2[2][17][NWAVE];

    const int t = threadIdx.x;
    const int c  = blockIdx.x / (BB / GG);    // c-major: blocks share W-slice
    const int b0 = (blockIdx.x % (BB / GG)) * GG;
    const int wv = t >> 6, l = t & 63;
    const int rg = t >> 3, p = t & 7;         // phase 1: 96 r-rows x 8 lanes

    uint32_t* uA = u2;                        // batch b0
    uint32_t* uB = u2 + (size_t)RR * 8;       // batch b0+1
    uint32_t* wrA = uA + (size_t)rg * 8 + p;  // word p of row rg
    uint32_t* wrB = uB + (size_t)rg * 8 + p;

    const uint32_t* wbase = wb + ((size_t)rg * CC + c) * 64 + 4 * p;
    const uint32_t* xbase = xpk + ((size_t)b0 * RR + rg) * 4;
    const size_t WROW = (size_t)96 * CC * 64;   // 96 rows of W words
    const size_t XROW = (size_t)96 * 4;         // 96 rows of x words

    // ---- Phase 1: 6 straight-line 2-row bodies; 8 loads batched first ----
    float s00 = 0.f, s01 = 0.f, s10 = 0.f, s11 = 0.f;
#pragma unroll
    for (int it2 = 0; it2 < 6; ++it2) {
        const uint32_t* wpa = wbase + (size_t)(2 * it2) * WROW;
        const uint32_t* wpb = wbase + (size_t)(2 * it2 + 1) * WROW;
        const uint32_t* xpa = xbase + (size_t)(2 * it2) * XROW;
        const uint32_t* xpb = xbase + (size_t)(2 * it2 + 1) * XROW;
        // --- all 8 loads up front (batch depth 8) ---
        uint4 wq0a = *reinterpret_cast<const uint4*>(wpa);
        uint4 wq1a = *reinterpret_cast<const uint4*>(wpa + 32);
        uint4 wq0b = *reinterpret_cast<const uint4*>(wpb);
        uint4 wq1b = *reinterpret_cast<const uint4*>(wpb + 32);
        uint4 xq0a = *reinterpret_cast<const uint4*>(xpa);
        uint4 xq1a = *reinterpret_cast<const uint4*>(xpa + (size_t)RR * 4);
        uint4 xq0b = *reinterpret_cast<const uint4*>(xpb);
        uint4 xq1b = *reinterpret_cast<const uint4*>(xpb + (size_t)RR * 4);
        // --- row a (r = 2*it2*96 + rg) ---
        {
            float d0, d1, e0, e1;
            DOT8P(wq0a, xq0a, d0);
            DOT8P(wq1a, xq0a, d1);
            DOT8P(wq0a, xq1a, e0);
            DOT8P(wq1a, xq1a, e1);
            s00 += d0; s01 += d1; s10 += e0; s11 += e1;
            wrA[(size_t)(2 * it2) * 768] = cvtpk(d0, d1);
            wrB[(size_t)(2 * it2) * 768] = cvtpk(e0, e1);
        }
        // --- row b (r = (2*it2+1)*96 + rg) ---
        {
            float d0, d1, e0, e1;
            DOT8P(wq0b, xq0b, d0);
            DOT8P(wq1b, xq0b, d1);
            DOT8P(wq0b, xq1b, e0);
            DOT8P(wq1b, xq1b, e1);
            s00 += d0; s01 += d1; s10 += e0; s11 += e1;
            wrA[(size_t)(2 * it2 + 1) * 768] = cvtpk(d0, d1);
            wrB[(size_t)(2 * it2 + 1) * 768] = cvtpk(e0, e1);
        }
    }
    // pass-0 reduce over the 8 row-lanes sharing p: ror8 (DPP) + shfl 16,32
    s00 = rr8add(s00); s01 = rr8add(s01);
    s10 = rr8add(s10); s11 = rr8add(s11);
#pragma unroll
    for (int m = 16; m < 64; m <<= 1) {
        s00 += __shfl_xor(s00, m); s01 += __shfl_xor(s01, m);
        s10 += __shfl_xor(s10, m); s11 += __shfl_xor(s11, m);
    }
    if (l < 8) {                              // lane l == p
        p0s[wv][l][0][0] = s00; p0s[wv][l][1][0] = s01;
        p0s[wv][l][0][1] = s10; p0s[wv][l][1][1] = s11;
    }
    __syncthreads();                          // BARRIER 1 of 3

    // ---- Phase-2 mapping ----
    const int g2 = wv / WPG;                  // waves 0-5: g=0, 6-11: g=1
    const int wv6 = wv - g2 * WPG;
    const uint32_t* ug = g2 ? uB : uA;
    const int q = l & 3;                      // owns o in {2q,2q+1,2q+8,2q+9}
    const int rl = l >> 2;
    const int rbase = wv6 * 16 + rl;
    const uint32_t* rp = ug + (size_t)rbase * 8 + 2 * q;

    const int oo = l & 15;                    // lane's redundant-squash o
    const int gb = l & 48;
    const int t0 = gb | (2 * q), t1 = gb | (2 * q + 1);
    const int t2 = gb | (2 * q + 8), t3 = gb | (2 * q + 9);

    // ---- v0 computed redundantly by all lanes ----
    float ra, rb, rc, rd;
    {
        float sv = 0.f;
#pragma unroll
        for (int w = 0; w < NWAVE; ++w) sv += p0s[w][oo & 7][oo >> 3][g2];
        sv *= (1.0f / RR);                    // softmax(0) = 1/R
        float ss = sv * sv;                   // 16-lane row sum, all DPP
        ss = qpadd1(ss); ss = qpadd2(ss); ss = rr4add(ss); ss = rr8add(ss);
        float vv = sv * (ss / ((1.0f + ss) * sqrtf(ss + 1e-7f)));
        ra = __shfl(vv, t0); rb = __shfl(vv, t1);
        rc = __shfl(vv, t2); rd = __shfl(vv, t3);
    }

    // ---- Phase 2: passes 1 and 2; one barrier each ----
#pragma unroll
    for (int pass = 1; pass < 3; ++pass) {
        const float2v WQA = { ra * LOG2E, rc * LOG2E };
        const float2v WQB = { rb * LOG2E, rd * LOG2E };
        float2v N0 = { 0.f, 0.f }, N1 = { 0.f, 0.f };
        float den = 0.f;

#pragma unroll
        for (int it2 = 0; it2 < 12; ++it2) {
            uint2 pp = *reinterpret_cast<const uint2*>(rp + (size_t)it2 * 768);
            float a_, b_, c_, d_;
            unpack2(pp.x, a_, b_);            // (u[2q],   u[2q+8])
            unpack2(pp.y, c_, d_);            // (u[2q+1], u[2q+9])
            float2v P0 = { a_, b_ };
            float2v P1 = { c_, d_ };
            float2v lg2 = __builtin_elementwise_fma(P0, WQA, P1 * WQB);
            float lg = lg2.x + lg2.y;
            lg = qpadd1(lg);                  // + lane^1 (quad partial)
            lg = qpadd2(lg);                  // + lane^2: full 16-o logit
            float e = EXP2(lg);               // == exp(raw logit)
            den += e;                         // same-q lanes: distinct r's
            float2v E2 = { e, e };
            N0 = __builtin_elementwise_fma(E2, P0, N0);
            N1 = __builtin_elementwise_fma(E2, P1, N1);
        }

        // stride-4-group reduce: ror4+ror8 (DPP) then shfl 16,32
        float n0 = N0.x, n2 = N0.y, n1 = N1.x, n3 = N1.y;
        n0 = rr4add(n0); n1 = rr4add(n1); n2 = rr4add(n2); n3 = rr4add(n3);
        den = rr4add(den);
        n0 = rr8add(n0); n1 = rr8add(n1); n2 = rr8add(n2); n3 = rr8add(n3);
        den = rr8add(den);
#pragma unroll
        for (int m = 16; m < 64; m <<= 1) {
            n0 += __shfl_xor(n0, m); n1 += __shfl_xor(n1, m);
            n2 += __shfl_xor(n2, m); n3 += __shfl_xor(n3, m);
            den += __shfl_xor(den, m);
        }
        const int pb = pass & 1;
        if (l < 4) {                          // lane l == q
            part2[pb][2 * l][wv]     = n0;
            part2[pb][2 * l + 1][wv] = n1;
            part2[pb][2 * l + 8][wv] = n2;
            part2[pb][2 * l + 9][wv] = n3;
            if (l == 0) part2[pb][16][wv] = den;
        }
        __syncthreads();                      // BARRIERS 2,3

        const float* po = &part2[pb][oo][0];
        const float* pd = &part2[pb][16][0];
        float nf = 0.f, df = 0.f;
#pragma unroll
        for (int w = 0; w < WPG; ++w) {
            nf += po[g2 * WPG + w];
            df += pd[g2 * WPG + w];
        }
        float s2 = nf / df;
        float ss2 = s2 * s2;                  // 16-lane row sum, all DPP
        ss2 = qpadd1(ss2); ss2 = qpadd2(ss2);
        ss2 = rr4add(ss2); ss2 = rr8add(ss2);
        float vv2 = s2 * (ss2 / ((1.0f + ss2) * sqrtf(ss2 + 1e-7f)));

        if (pass == 1) {                      // accumulate weights in regs
            ra += __shfl(vv2, t0); rb += __shfl(vv2, t1);
            rc += __shfl(vv2, t2); rd += __shfl(vv2, t3);
        } else {
            if ((wv == 0 || wv == WPG) && l < 16)
                out[((size_t)(b0 + g2) * CC + c) * OO + oo] = vv2;
        }
    }
}

extern "C" void kernel_launch(void* const* d_in, const int* in_sizes, int n_in,
                              void* d_out, int out_size, void* d_ws, size_t ws_size,
                              hipStream_t stream) {
    const float* x = (const float*)d_in[0];  // (B,R,I) fp32
    const float* W = (const float*)d_in[1];  // (R,C,O,I) fp32
    if (n_in >= 2 && in_sizes[0] == RR * CC * OO * II &&
        in_sizes[1] == BB * RR * II) {
        const float* tmp = x; x = W; W = tmp;
    }
    float* out = (float*)d_out;              // (B,1,C,O,1) fp32
    uint32_t* wbf = (uint32_t*)d_ws;         // packed-bf16 W (2.95 MB)
    uint32_t* xpk = wbf + WSWORDS;           // packed-bf16 x (4.72 MB)

    const int cvt_blocks = (int)((XWORDS / 4 + 255) / 256);   // 1152
    k_cvt<<<cvt_blocks, 256, 0, stream>>>(W, x, wbf, xpk);

    const size_t dyn_lds = (size_t)GG * RR * 8 * 4;   // 73,728 B
    k_caps<<<CC * (BB / GG), NT, dyn_lds, stream>>>(xpk, wbf, out);
}